// Round 10
// baseline (466.882 us; speedup 1.0000x reference)
//
#include <hip/hip_runtime.h>
#include <math.h>

#define N_PTS  131072
#define DIM    128
#define NBOOK  4
#define KCODES 1024

#define CHUNK   32                   // codes per LDS chunk
#define NCHB    32                   // chunks per book
#define PT      2                    // point tiles (32 pts each) per wave -> 64 pts/wave
#define BPTS    256                  // 4 waves * 64 points
#define SLOTS   9                    // 8 f16 A-slots + 1 csq slot
#define CHUNK_BYTES (SLOTS * 1024)   // 9216 B
#define CHUNK_U16   (SLOTS * 512)    // 4608
#define EPS_ACC 0.05f                // >7 sigma of f16 dot error + pack slop
#define WLB_CAP 32768                // per-book worklist cap

typedef _Float16 f16x8 __attribute__((ext_vector_type(8)));
typedef float    f32x16 __attribute__((ext_vector_type(16)));
typedef unsigned short u16;
typedef unsigned long long u64;

// ws layout: cbf f16 (4*32*9216 = 1179648 B) | results u64[4][32768] (1 MB, in the gap)
//            | csq fp32[4096] | counters int[4] | worklist int[4][32768]
#define WS_RES_OFF  1179648u
#define WS_CSQ_OFF  2359296u
#define WS_CNT_OFF  (WS_CSQ_OFF + 16384u)
#define WS_WL_OFF   (WS_CNT_OFF + 256u)

__device__ inline u16 f16bits(_Float16 h) {
    union { _Float16 f; u16 u; } c; c.f = h; return c.u;
}

__device__ inline void async_copy16(const void* g, void* l) {
    __builtin_amdgcn_global_load_lds(
        (const __attribute__((address_space(1))) void*)g,
        (__attribute__((address_space(3))) void*)l,
        16, 0, 0);
}

// ---------------- prep: codebook -> f16 A-fragments (32x32x16) + csq slot + csq --------
// cbf per (b,chunk): slot s(0..7) at s*1024: A-frag f16 of dims [s*16, s*16+16)
//   frag: row(code-in-chunk) = lane&31, k = (lane>>5)*8 + j  (same k-map as B side)
// slot 8 at 8192: csq slice: lanes<32: k0=csq_hi,k1=csq_mid,k2=csq_rem (x -0.5), k3=320 (x 1.0)
__global__ __launch_bounds__(256)
void prep_kernel(const float* __restrict__ cb, char* __restrict__ cbf,
                 float* __restrict__ csq, int* __restrict__ counters) {
    if (blockIdx.x >= 256) {                       // csq + csq-slot + counter blocks (16)
        int idx = (blockIdx.x - 256) * 256 + threadIdx.x;   // 0..4095
        if (idx < 4) counters[idx] = 0;
        const float4* p = (const float4*)(cb + (size_t)idx * DIM);
        float s = 0.f;
#pragma unroll
        for (int i = 0; i < DIM / 4; ++i) {
            float4 v = p[i];
            s += v.x * v.x + v.y * v.y + v.z * v.z + v.w * v.w;
        }
        csq[idx] = s;
        int b = idx >> 10, k = idx & 1023;
        _Float16 hi  = (_Float16)s;
        float    r1  = s - (float)hi;
        _Float16 mid = (_Float16)r1;
        _Float16 rem = (_Float16)(r1 - (float)mid);
        u16* dst = (u16*)(cbf + (size_t)(b * 32 + (k >> 5)) * CHUNK_BYTES
                              + 8192 + (size_t)(k & 31) * 16);
        u16 o[8] = {f16bits(hi), f16bits(mid), f16bits(rem), (u16)0x5D00, 0, 0, 0, 0};
#pragma unroll
        for (int j = 0; j < 8; ++j) dst[j] = o[j];
        u16* dz = dst + 32 * 8;                    // lanes 32..63 of slot 8 = 0
#pragma unroll
        for (int j = 0; j < 8; ++j) dz[j] = 0;
        return;
    }
    int t    = blockIdx.x * 256 + threadIdx.x;     // 0..65535
    int lane = t & 63;
    int s    = (t >> 6) & 7;
    int bc   = t >> 9;                             // 0..127  (b*32 + chunk)
    int code = (bc & 31) * CHUNK + (lane & 31);
    int b    = bc >> 5;
    int dd   = s * 16 + (lane >> 5) * 8;

    const float* row = cb + ((size_t)b * KCODES + code) * DIM + dd;
    float4 v0 = ((const float4*)row)[0];
    float4 v1 = ((const float4*)row)[1];
    float vals[8] = {v0.x, v0.y, v0.z, v0.w, v1.x, v1.y, v1.z, v1.w};
    u16 o[8];
#pragma unroll
    for (int j = 0; j < 8; ++j) o[j] = f16bits((_Float16)vals[j]);
    u16* dst = (u16*)(cbf + (size_t)bc * CHUNK_BYTES + (size_t)s * 1024 + (size_t)lane * 16);
#pragma unroll
    for (int j = 0; j < 8; ++j) dst[j] = o[j];
}

// ---------------- main: R0 skeleton, f16 single plane (9 MFMA/pt/chunk) -- UNCHANGED ---
// grid (512, 2): block y handles books {2y, 2y+1} as one 64-chunk stream
__global__ __launch_bounds__(256, 3)
void argmin_mfma_kernel(const float* __restrict__ x,
                        const u16*  __restrict__ cbf,
                        int* __restrict__ out,
                        int* __restrict__ counters,
                        int* __restrict__ worklist,
                        u64* __restrict__ results) {
    __shared__ u16 lds[2 * CHUNK_U16];             // 18432 B (two 9.2 KB buffers)

    const int tid  = threadIdx.x;
    const int lane = tid & 63;
    const int w    = tid >> 6;
    const int n0   = blockIdx.x * BPTS;
    const int col  = lane & 31;
    const int kh   = lane >> 5;

    const char* src0 = (const char*)cbf + (size_t)(blockIdx.y * 64) * CHUNK_BYTES;

    auto issue = [&](int c) {                      // stage chunk c -> buf[c&1]
        const char* src = src0 + (size_t)c * CHUNK_BYTES;
        char* dst = (char*)&lds[(c & 1) * CHUNK_U16];
#pragma unroll
        for (int i = 0; i < 2; ++i)
            async_copy16(src + i * 4096 + tid * 16, dst + i * 4096 + w * 1024);
        if (w == 0)
            async_copy16(src + 8192 + lane * 16, dst + 8192);
    };

    issue(0);                                      // chunk 0 in flight during x-convert

    // ---- B fragments (points), f16, in regs (overlaps chunk-0 staging) ----
    f16x8 xh[PT][8];
#pragma unroll
    for (int pt = 0; pt < PT; ++pt) {
        const float* xrow = x + (size_t)(n0 + w * 64 + pt * 32 + col) * DIM;
#pragma unroll
        for (int s = 0; s < 8; ++s) {
            const float* p = xrow + s * 16 + kh * 8;
            float4 v0 = *(const float4*)p;
            float4 v1 = *(const float4*)(p + 4);
            float vals[8] = {v0.x, v0.y, v0.z, v0.w, v1.x, v1.y, v1.z, v1.w};
            f16x8 hv;
#pragma unroll
            for (int j = 0; j < 8; ++j) hv[j] = (_Float16)vals[j];
            xh[pt][s] = hv;
        }
    }
    f16x8 xcf;                                     // csq-slice B frag
#pragma unroll
    for (int j = 0; j < 8; ++j) {
        _Float16 v = (_Float16)0.0f;
        if (kh == 0) {
            if (j < 3) v = (_Float16)(-0.5f);
            else if (j == 3) v = (_Float16)1.0f;
        }
        xcf[j] = v;
    }

    unsigned b1p[PT], b2p[PT];
    int bchunk[PT];
#pragma unroll
    for (int pt = 0; pt < PT; ++pt) { b1p[pt] = 0u; b2p[pt] = 0u; bchunk[pt] = 0; }

    auto mfma_chunk = [&](const u16* A, f32x16* ac) {
#pragma unroll
        for (int pt = 0; pt < PT; ++pt)
#pragma unroll
            for (int r = 0; r < 16; ++r) ac[pt][r] = 0.f;
#pragma unroll
        for (int s = 0; s < 8; ++s) {
            f16x8 ah = *(const f16x8*)&A[s * 512 + lane * 8];
#pragma unroll
            for (int pt = 0; pt < PT; ++pt)
                ac[pt] = __builtin_amdgcn_mfma_f32_32x32x16_f16(ah, xh[pt][s], ac[pt], 0, 0, 0);
        }
        f16x8 acs = *(const f16x8*)&A[8 * 512 + lane * 8];
#pragma unroll
        for (int pt = 0; pt < PT; ++pt)                 // acc = dot - csq/2 + 320
            ac[pt] = __builtin_amdgcn_mfma_f32_32x32x16_f16(acs, xcf, ac[pt], 0, 0, 0);
    };

    auto epilogue = [&](const f32x16* ac, int cc) {     // packed top-2, larger = nearer
        int ci = cc & 31;
#pragma unroll
        for (int pt = 0; pt < PT; ++pt) {
            unsigned prev = b1p[pt], p1v = prev, p2v = b2p[pt];
#pragma unroll
            for (int r = 0; r < 16; r += 2) {
                unsigned pa = (__float_as_uint(ac[pt][r])     & 0xFFFFFFE0u) | (31u - (unsigned)r);
                unsigned pb = (__float_as_uint(ac[pt][r + 1]) & 0xFFFFFFE0u) | (30u - (unsigned)r);
                unsigned hi = pa > pb ? pa : pb;
                unsigned lo = pa < pb ? pa : pb;
                unsigned t2 = hi < p1v ? hi : p1v;
                unsigned m  = lo > t2 ? lo : t2;
                p2v = p2v > m ? p2v : m;                // -> v_max3
                p1v = p1v > hi ? p1v : hi;
            }
            bchunk[pt] = (p1v != prev) ? ci : bchunk[pt];
            b1p[pt] = p1v; b2p[pt] = p2v;
        }
    };

    auto finalize = [&](int book) {
        int b = blockIdx.y * 2 + book;
#pragma unroll
        for (int pt = 0; pt < PT; ++pt) {
            unsigned r = 31u - (b1p[pt] & 31u);         // leaf 0..15
            float m1 = __uint_as_float(b1p[pt] & 0xFFFFFFE0u);
            float m2 = __uint_as_float(b2p[pt] & 0xFFFFFFE0u);
            int row = (int)((r & 3u) + 8u * (r >> 2)) + 4 * kh;
            int code = bchunk[pt] * CHUNK + row;
            float om1 = __shfl_xor(m1, 32);
            float om2 = __shfl_xor(m2, 32);
            int   oc  = __shfl_xor(code, 32);
            bool take = (om1 > m1) || (om1 == m1 && oc < code);
            float nm2 = fmaxf(fminf(m1, om1), fmaxf(m2, om2));
            if (take) { m1 = om1; code = oc; }
            m2 = nm2;
            if (lane < 32) {
                int point = n0 + w * 64 + pt * 32 + col;
                out[point * NBOOK + b] = code;
                if (m1 - m2 < EPS_ACC) {
                    int pos = atomicAdd(&counters[b], 1);
                    if (pos < WLB_CAP) {
                        worklist[b * WLB_CAP + pos] = point;
                        results[b * WLB_CAP + pos] = 0xFFFFFFFFFFFFFFFFull;
                    }
                }
            }
            b1p[pt] = 0u; b2p[pt] = 0u; bchunk[pt] = 0;
        }
    };

    __syncthreads();                               // chunk 0 visible

    f32x16 acc0[PT], acc1[PT];
    for (int c = 0; c < 64; c += 2) {
        // ---- even chunk: buf0/acc0; epilogue of odd chunk c-1 deferred here ----
        issue(c + 1);
        mfma_chunk(lds, acc0);
        if (c > 0) {
            epilogue(acc1, c - 1);
            if (c == 32) finalize(0);              // after chunk31 epilogue
        }
        __syncthreads();                           // loads c+1 done; buf0 reads done

        // ---- odd chunk: buf1/acc1; epilogue of even chunk c deferred here ----
        if (c + 2 < 64) issue(c + 2);
        mfma_chunk(lds + CHUNK_U16, acc1);
        epilogue(acc0, c);
        __syncthreads();                           // loads c+2 done; buf1 reads done
    }
    epilogue(acc1, 63);
    finalize(1);
}

// ---------------- fallback: exact fp32, LANE-STATIONARY items, broadcast codes ---------
// grid (512, 4): y = book. Unit = (64-item tile) x (code octant of 128). Each lane holds
// ONE item's full x-row in 32 float4 VGPRs (static indexing); all 64 lanes scan the SAME
// code rows via wave-uniform (broadcast) loads -> no cross-lane shuffles, no scattered
// reads in the hot loop. Per wave-code: 32 broadcast b128 loads + 128 fma for 64 dots.
// Octants combined via 64-bit atomicMin key (monotone(dist)<<32 | code): min dist,
// tie -> min code (reference order). Tail lanes clamp to item 0 (duplicate valid work).
__global__ __launch_bounds__(256)
void exact_kernel(const float* __restrict__ x,
                  const float* __restrict__ cb,
                  const float* __restrict__ csq,
                  const int* __restrict__ counters,
                  const int* __restrict__ worklist,
                  u64* __restrict__ results) {
    const int b = blockIdx.y;
    int n = counters[b];
    if (n > WLB_CAP) n = WLB_CAP;
    if (n == 0) return;
    const int lane = threadIdx.x & 63;
    const int w    = threadIdx.x >> 6;
    const float* cbb = cb + (size_t)b * KCODES * DIM;
    const float* csb = csq + b * KCODES;

    int ntiles = (n + 63) >> 6;
    int units  = ntiles * 8;
    for (int u = blockIdx.x * 4 + w; u < units; u += gridDim.x * 4) {
        int tile = u >> 3, q = u & 7;
        int ii = tile * 64 + lane;
        int iw = ii < n ? ii : 0;                  // clamp -> duplicate of item 0, harmless
        int point = worklist[b * WLB_CAP + iw];

        const float4* xr4 = (const float4*)(x + (size_t)point * DIM);
        float4 xr[32];
#pragma unroll
        for (int j = 0; j < 32; ++j) xr[j] = xr4[j];

        float bd = 3.4e38f;
        int   bi = 0;
        int   c0 = q * 128;
        for (int cc = 0; cc < 128; ++cc) {
            int c = c0 + cc;
            const float4* cr = (const float4*)(cbb + (size_t)c * DIM);
            float ax = 0.f, ay = 0.f, az = 0.f, aw = 0.f;
#pragma unroll
            for (int j = 0; j < 32; ++j) {
                float4 cv = cr[j];                 // wave-uniform addr -> broadcast
                ax = fmaf(cv.x, xr[j].x, ax);
                ay = fmaf(cv.y, xr[j].y, ay);
                az = fmaf(cv.z, xr[j].z, az);
                aw = fmaf(cv.w, xr[j].w, aw);
            }
            float dist = csb[c] - 2.f * ((ax + ay) + (az + aw));
            if (dist < bd) { bd = dist; bi = c; }  // ascending c -> lowest idx kept
        }
        unsigned ub = __float_as_uint(bd);
        ub = (ub & 0x80000000u) ? ~ub : (ub | 0x80000000u);   // monotone f32->u32
        u64 key = ((u64)ub << 32) | (unsigned)bi;
        atomicMin(&results[b * WLB_CAP + iw], key);
    }
}

// ---------------- writer: unpack winning codes to out ----------------------------------
__global__ __launch_bounds__(256)
void write_kernel(const int* __restrict__ counters,
                  const int* __restrict__ worklist,
                  const u64* __restrict__ results,
                  int* __restrict__ out) {
    const int b = blockIdx.y;
    int n = counters[b];
    if (n > WLB_CAP) n = WLB_CAP;
    for (int i = blockIdx.x * 256 + threadIdx.x; i < n; i += gridDim.x * 256) {
        int point = worklist[b * WLB_CAP + i];
        out[point * NBOOK + b] = (int)(results[b * WLB_CAP + i] & 1023u);
    }
}

extern "C" void kernel_launch(void* const* d_in, const int* in_sizes, int n_in,
                              void* d_out, int out_size, void* d_ws, size_t ws_size,
                              hipStream_t stream) {
    const float* x  = (const float*)d_in[0];   // [N, D] fp32
    const float* cb = (const float*)d_in[1];   // [B, K, D] fp32
    int* out = (int*)d_out;                    // [N, B] int32

    char* ws = (char*)d_ws;
    u16*   cbf      = (u16*)ws;
    u64*   results  = (u64*)(ws + WS_RES_OFF);
    float* csq      = (float*)(ws + WS_CSQ_OFF);
    int*   counters = (int*)(ws + WS_CNT_OFF);
    int*   worklist = (int*)(ws + WS_WL_OFF);

    prep_kernel<<<272, 256, 0, stream>>>(cb, (char*)cbf, csq, counters);

    argmin_mfma_kernel<<<dim3(N_PTS / BPTS, 2), 256, 0, stream>>>(x, cbf, out, counters,
                                                                  worklist, results);

    exact_kernel<<<dim3(512, 4), 256, 0, stream>>>(x, cb, csq, counters, worklist, results);

    write_kernel<<<dim3(32, 4), 256, 0, stream>>>(counters, worklist, results, out);
}

// Round 11
// 342.306 us; speedup vs baseline: 1.3639x; 1.3639x over previous
//
#include <hip/hip_runtime.h>
#include <math.h>

#define N_PTS  131072
#define DIM    128
#define NBOOK  4
#define KCODES 1024

#define CHUNK   32                   // codes per LDS chunk
#define NCHB    32                   // chunks per book
#define PT      2                    // point tiles (32 pts each) per wave -> 64 pts/wave
#define BPTS    256                  // 4 waves * 64 points
#define SLOTS   9                    // 8 f16 A-slots + 1 csq slot
#define CHUNK_BYTES (SLOTS * 1024)   // 9216 B
#define CHUNK_U16   (SLOTS * 512)    // 4608
#define EPS_ACC 0.05f                // >7 sigma of f16 dot error + pack slop
#define WLB_CAP 32768                // per-book worklist cap

typedef _Float16 f16x8 __attribute__((ext_vector_type(8)));
typedef float    f32x16 __attribute__((ext_vector_type(16)));
typedef unsigned short u16;
typedef unsigned long long u64;

// ws layout: cbf f16 (4*32*9216 = 1179648 B) | results u64[4][32768] (1 MB, in the gap)
//            | csq fp32[4096] | counters int[4] | worklist int[4][32768]
#define WS_RES_OFF  1179648u
#define WS_CSQ_OFF  2359296u
#define WS_CNT_OFF  (WS_CSQ_OFF + 16384u)
#define WS_WL_OFF   (WS_CNT_OFF + 256u)

__device__ inline u16 f16bits(_Float16 h) {
    union { _Float16 f; u16 u; } c; c.f = h; return c.u;
}

__device__ inline void async_copy16(const void* g, void* l) {
    __builtin_amdgcn_global_load_lds(
        (const __attribute__((address_space(1))) void*)g,
        (__attribute__((address_space(3))) void*)l,
        16, 0, 0);
}

// ---------------- prep: codebook -> f16 A-fragments (32x32x16) + csq slot + csq --------
// cbf per (b,chunk): slot s(0..7) at s*1024: A-frag f16 of dims [s*16, s*16+16)
//   frag: row(code-in-chunk) = lane&31, k = (lane>>5)*8 + j  (same k-map as B side)
// slot 8 at 8192: csq slice: lanes<32: k0=csq_hi,k1=csq_mid,k2=csq_rem (x -0.5), k3=320 (x 1.0)
__global__ __launch_bounds__(256)
void prep_kernel(const float* __restrict__ cb, char* __restrict__ cbf,
                 float* __restrict__ csq, int* __restrict__ counters) {
    if (blockIdx.x >= 256) {                       // csq + csq-slot + counter blocks (16)
        int idx = (blockIdx.x - 256) * 256 + threadIdx.x;   // 0..4095
        if (idx < 4) counters[idx] = 0;
        const float4* p = (const float4*)(cb + (size_t)idx * DIM);
        float s = 0.f;
#pragma unroll
        for (int i = 0; i < DIM / 4; ++i) {
            float4 v = p[i];
            s += v.x * v.x + v.y * v.y + v.z * v.z + v.w * v.w;
        }
        csq[idx] = s;
        int b = idx >> 10, k = idx & 1023;
        _Float16 hi  = (_Float16)s;
        float    r1  = s - (float)hi;
        _Float16 mid = (_Float16)r1;
        _Float16 rem = (_Float16)(r1 - (float)mid);
        u16* dst = (u16*)(cbf + (size_t)(b * 32 + (k >> 5)) * CHUNK_BYTES
                              + 8192 + (size_t)(k & 31) * 16);
        u16 o[8] = {f16bits(hi), f16bits(mid), f16bits(rem), (u16)0x5D00, 0, 0, 0, 0};
#pragma unroll
        for (int j = 0; j < 8; ++j) dst[j] = o[j];
        u16* dz = dst + 32 * 8;                    // lanes 32..63 of slot 8 = 0
#pragma unroll
        for (int j = 0; j < 8; ++j) dz[j] = 0;
        return;
    }
    int t    = blockIdx.x * 256 + threadIdx.x;     // 0..65535
    int lane = t & 63;
    int s    = (t >> 6) & 7;
    int bc   = t >> 9;                             // 0..127  (b*32 + chunk)
    int code = (bc & 31) * CHUNK + (lane & 31);
    int b    = bc >> 5;
    int dd   = s * 16 + (lane >> 5) * 8;

    const float* row = cb + ((size_t)b * KCODES + code) * DIM + dd;
    float4 v0 = ((const float4*)row)[0];
    float4 v1 = ((const float4*)row)[1];
    float vals[8] = {v0.x, v0.y, v0.z, v0.w, v1.x, v1.y, v1.z, v1.w};
    u16 o[8];
#pragma unroll
    for (int j = 0; j < 8; ++j) o[j] = f16bits((_Float16)vals[j]);
    u16* dst = (u16*)(cbf + (size_t)bc * CHUNK_BYTES + (size_t)s * 1024 + (size_t)lane * 16);
#pragma unroll
    for (int j = 0; j < 8; ++j) dst[j] = o[j];
}

// ---------------- main: R0 skeleton, f16 single plane (9 MFMA/pt/chunk) -- UNCHANGED ---
// grid (512, 2): block y handles books {2y, 2y+1} as one 64-chunk stream
__global__ __launch_bounds__(256, 3)
void argmin_mfma_kernel(const float* __restrict__ x,
                        const u16*  __restrict__ cbf,
                        int* __restrict__ out,
                        int* __restrict__ counters,
                        int* __restrict__ worklist,
                        u64* __restrict__ results) {
    __shared__ u16 lds[2 * CHUNK_U16];             // 18432 B (two 9.2 KB buffers)

    const int tid  = threadIdx.x;
    const int lane = tid & 63;
    const int w    = tid >> 6;
    const int n0   = blockIdx.x * BPTS;
    const int col  = lane & 31;
    const int kh   = lane >> 5;

    const char* src0 = (const char*)cbf + (size_t)(blockIdx.y * 64) * CHUNK_BYTES;

    auto issue = [&](int c) {                      // stage chunk c -> buf[c&1]
        const char* src = src0 + (size_t)c * CHUNK_BYTES;
        char* dst = (char*)&lds[(c & 1) * CHUNK_U16];
#pragma unroll
        for (int i = 0; i < 2; ++i)
            async_copy16(src + i * 4096 + tid * 16, dst + i * 4096 + w * 1024);
        if (w == 0)
            async_copy16(src + 8192 + lane * 16, dst + 8192);
    };

    issue(0);                                      // chunk 0 in flight during x-convert

    // ---- B fragments (points), f16, in regs (overlaps chunk-0 staging) ----
    f16x8 xh[PT][8];
#pragma unroll
    for (int pt = 0; pt < PT; ++pt) {
        const float* xrow = x + (size_t)(n0 + w * 64 + pt * 32 + col) * DIM;
#pragma unroll
        for (int s = 0; s < 8; ++s) {
            const float* p = xrow + s * 16 + kh * 8;
            float4 v0 = *(const float4*)p;
            float4 v1 = *(const float4*)(p + 4);
            float vals[8] = {v0.x, v0.y, v0.z, v0.w, v1.x, v1.y, v1.z, v1.w};
            f16x8 hv;
#pragma unroll
            for (int j = 0; j < 8; ++j) hv[j] = (_Float16)vals[j];
            xh[pt][s] = hv;
        }
    }
    f16x8 xcf;                                     // csq-slice B frag
#pragma unroll
    for (int j = 0; j < 8; ++j) {
        _Float16 v = (_Float16)0.0f;
        if (kh == 0) {
            if (j < 3) v = (_Float16)(-0.5f);
            else if (j == 3) v = (_Float16)1.0f;
        }
        xcf[j] = v;
    }

    unsigned b1p[PT], b2p[PT];
    int bchunk[PT];
#pragma unroll
    for (int pt = 0; pt < PT; ++pt) { b1p[pt] = 0u; b2p[pt] = 0u; bchunk[pt] = 0; }

    auto mfma_chunk = [&](const u16* A, f32x16* ac) {
#pragma unroll
        for (int pt = 0; pt < PT; ++pt)
#pragma unroll
            for (int r = 0; r < 16; ++r) ac[pt][r] = 0.f;
#pragma unroll
        for (int s = 0; s < 8; ++s) {
            f16x8 ah = *(const f16x8*)&A[s * 512 + lane * 8];
#pragma unroll
            for (int pt = 0; pt < PT; ++pt)
                ac[pt] = __builtin_amdgcn_mfma_f32_32x32x16_f16(ah, xh[pt][s], ac[pt], 0, 0, 0);
        }
        f16x8 acs = *(const f16x8*)&A[8 * 512 + lane * 8];
#pragma unroll
        for (int pt = 0; pt < PT; ++pt)                 // acc = dot - csq/2 + 320
            ac[pt] = __builtin_amdgcn_mfma_f32_32x32x16_f16(acs, xcf, ac[pt], 0, 0, 0);
    };

    auto epilogue = [&](const f32x16* ac, int cc) {     // packed top-2, larger = nearer
        int ci = cc & 31;
#pragma unroll
        for (int pt = 0; pt < PT; ++pt) {
            unsigned prev = b1p[pt], p1v = prev, p2v = b2p[pt];
#pragma unroll
            for (int r = 0; r < 16; r += 2) {
                unsigned pa = (__float_as_uint(ac[pt][r])     & 0xFFFFFFE0u) | (31u - (unsigned)r);
                unsigned pb = (__float_as_uint(ac[pt][r + 1]) & 0xFFFFFFE0u) | (30u - (unsigned)r);
                unsigned hi = pa > pb ? pa : pb;
                unsigned lo = pa < pb ? pa : pb;
                unsigned t2 = hi < p1v ? hi : p1v;
                unsigned m  = lo > t2 ? lo : t2;
                p2v = p2v > m ? p2v : m;                // -> v_max3
                p1v = p1v > hi ? p1v : hi;
            }
            bchunk[pt] = (p1v != prev) ? ci : bchunk[pt];
            b1p[pt] = p1v; b2p[pt] = p2v;
        }
    };

    auto finalize = [&](int book) {
        int b = blockIdx.y * 2 + book;
#pragma unroll
        for (int pt = 0; pt < PT; ++pt) {
            unsigned r = 31u - (b1p[pt] & 31u);         // leaf 0..15
            float m1 = __uint_as_float(b1p[pt] & 0xFFFFFFE0u);
            float m2 = __uint_as_float(b2p[pt] & 0xFFFFFFE0u);
            int row = (int)((r & 3u) + 8u * (r >> 2)) + 4 * kh;
            int code = bchunk[pt] * CHUNK + row;
            float om1 = __shfl_xor(m1, 32);
            float om2 = __shfl_xor(m2, 32);
            int   oc  = __shfl_xor(code, 32);
            bool take = (om1 > m1) || (om1 == m1 && oc < code);
            float nm2 = fmaxf(fminf(m1, om1), fmaxf(m2, om2));
            if (take) { m1 = om1; code = oc; }
            m2 = nm2;
            if (lane < 32) {
                int point = n0 + w * 64 + pt * 32 + col;
                out[point * NBOOK + b] = code;
                if (m1 - m2 < EPS_ACC) {
                    int pos = atomicAdd(&counters[b], 1);
                    if (pos < WLB_CAP) {
                        worklist[b * WLB_CAP + pos] = point;
                        results[b * WLB_CAP + pos] = 0xFFFFFFFFFFFFFFFFull;
                    }
                }
            }
            b1p[pt] = 0u; b2p[pt] = 0u; bchunk[pt] = 0;
        }
    };

    __syncthreads();                               // chunk 0 visible

    f32x16 acc0[PT], acc1[PT];
    for (int c = 0; c < 64; c += 2) {
        // ---- even chunk: buf0/acc0; epilogue of odd chunk c-1 deferred here ----
        issue(c + 1);
        mfma_chunk(lds, acc0);
        if (c > 0) {
            epilogue(acc1, c - 1);
            if (c == 32) finalize(0);              // after chunk31 epilogue
        }
        __syncthreads();                           // loads c+1 done; buf0 reads done

        // ---- odd chunk: buf1/acc1; epilogue of even chunk c deferred here ----
        if (c + 2 < 64) issue(c + 2);
        mfma_chunk(lds + CHUNK_U16, acc1);
        epilogue(acc0, c);
        __syncthreads();                           // loads c+2 done; buf1 reads done
    }
    epilogue(acc1, 63);
    finalize(1);
}

// ---------------- fallback: exact fp32, CODE-STATIONARY regs, items stream via LDS -----
// grid (128, 4): y = book; x = replica r (32) x code-quarter q (4). Each lane OWNS one
// code row in 32 float4 VGPRs (loaded from L2 once per block -> codebook traffic 64 MB
// total vs 4 GB re-read). Items i = r, r+R, ... stream through a double-buffered 512 B
// LDS slot (staged by wave 0 via one global_load_lds while everyone computes). Dot is
// fully lane-local: 32 broadcast ds_reads + 128 FMA per item; wave argmin-reduce
// (tie -> min code) then u64 atomicMin key combines quarters/replicas.
__global__ __launch_bounds__(256, 2)
void exact_kernel(const float* __restrict__ x,
                  const float* __restrict__ cb,
                  const float* __restrict__ csq,
                  const int* __restrict__ counters,
                  const int* __restrict__ worklist,
                  u64* __restrict__ results) {
    __shared__ float4 xsl[2][32];                  // two 512 B x-row buffers

    const int b = blockIdx.y;
    int n = counters[b];
    if (n > WLB_CAP) n = WLB_CAP;
    if (n == 0) return;
    const int tid  = threadIdx.x;
    const int lane = tid & 63;
    const int w    = tid >> 6;
    const int q    = blockIdx.x & 3;               // code quarter
    const int r    = blockIdx.x >> 2;              // replica 0..R-1
    const int R    = gridDim.x >> 2;               // 32

    const int c = q * 256 + w * 64 + lane;         // my code (one per lane)
    const float4* cr4 = (const float4*)(cb + ((size_t)b * KCODES + c) * DIM);
    float4 crow[32];
#pragma unroll
    for (int j = 0; j < 32; ++j) crow[j] = cr4[j]; // one-time L2 read, stays in VGPRs
    const float mycsq = csq[b * KCODES + c];

    if (r < n) {                                   // stage first item
        int p0 = worklist[b * WLB_CAP + r];
        if (tid < 32)
            async_copy16(x + (size_t)p0 * DIM + tid * 4, (char*)&xsl[0][0] + tid * 16);
    }
    __syncthreads();

    int cur = 0;
    for (int i = r; i < n; i += R) {
        int inext = i + R;
        if (inext < n) {                           // stage next while computing current
            int pn = worklist[b * WLB_CAP + inext];
            if (tid < 32)
                async_copy16(x + (size_t)pn * DIM + tid * 4,
                             (char*)&xsl[cur ^ 1][0] + tid * 16);
        }
        float ax = 0.f, ay = 0.f, az = 0.f, aw = 0.f;
#pragma unroll
        for (int j = 0; j < 32; ++j) {
            float4 xv = xsl[cur][j];               // uniform addr -> LDS broadcast
            ax = fmaf(crow[j].x, xv.x, ax);
            ay = fmaf(crow[j].y, xv.y, ay);
            az = fmaf(crow[j].z, xv.z, az);
            aw = fmaf(crow[j].w, xv.w, aw);
        }
        float bd = mycsq - 2.f * ((ax + ay) + (az + aw));
        int   bi = c;
#pragma unroll
        for (int off = 1; off <= 32; off <<= 1) {  // wave argmin, tie -> lowest code
            float od = __shfl_xor(bd, off);
            int   oi = __shfl_xor(bi, off);
            if (od < bd || (od == bd && oi < bi)) { bd = od; bi = oi; }
        }
        if (lane == 0) {
            unsigned ub = __float_as_uint(bd);
            ub = (ub & 0x80000000u) ? ~ub : (ub | 0x80000000u);   // monotone f32->u32
            u64 key = ((u64)ub << 32) | (unsigned)bi;
            atomicMin(&results[b * WLB_CAP + i], key);
        }
        __syncthreads();                           // staging landed; reads done
        cur ^= 1;
    }
}

// ---------------- writer: unpack winning codes to out ----------------------------------
__global__ __launch_bounds__(256)
void write_kernel(const int* __restrict__ counters,
                  const int* __restrict__ worklist,
                  const u64* __restrict__ results,
                  int* __restrict__ out) {
    const int b = blockIdx.y;
    int n = counters[b];
    if (n > WLB_CAP) n = WLB_CAP;
    for (int i = blockIdx.x * 256 + threadIdx.x; i < n; i += gridDim.x * 256) {
        int point = worklist[b * WLB_CAP + i];
        out[point * NBOOK + b] = (int)(results[b * WLB_CAP + i] & 1023u);
    }
}

extern "C" void kernel_launch(void* const* d_in, const int* in_sizes, int n_in,
                              void* d_out, int out_size, void* d_ws, size_t ws_size,
                              hipStream_t stream) {
    const float* x  = (const float*)d_in[0];   // [N, D] fp32
    const float* cb = (const float*)d_in[1];   // [B, K, D] fp32
    int* out = (int*)d_out;                    // [N, B] int32

    char* ws = (char*)d_ws;
    u16*   cbf      = (u16*)ws;
    u64*   results  = (u64*)(ws + WS_RES_OFF);
    float* csq      = (float*)(ws + WS_CSQ_OFF);
    int*   counters = (int*)(ws + WS_CNT_OFF);
    int*   worklist = (int*)(ws + WS_WL_OFF);

    prep_kernel<<<272, 256, 0, stream>>>(cb, (char*)cbf, csq, counters);

    argmin_mfma_kernel<<<dim3(N_PTS / BPTS, 2), 256, 0, stream>>>(x, cbf, out, counters,
                                                                  worklist, results);

    exact_kernel<<<dim3(128, 4), 256, 0, stream>>>(x, cb, csq, counters, worklist, results);

    write_kernel<<<dim3(32, 4), 256, 0, stream>>>(counters, worklist, results, out);
}